// Round 23
// baseline (279.305 us; speedup 1.0000x reference)
//
#include <hip/hip_runtime.h>
#include <hip/hip_bf16.h>
#include <cstddef>
#include <cstdint>

typedef __hip_bfloat16 bf16;
typedef __attribute__((ext_vector_type(8))) short bf16x8;   // 8 bf16 = 4 VGPRs
typedef __attribute__((ext_vector_type(4))) float f32x4;

#define NPT 4096   // points per cloud
#define BB  4      // batch
#define NBR 16     // neighbors (nsample)
#define WD  16     // weightnet output width
#define CDIM 64    // input feature channels
#define MIDD 128   // lin1/lin2 output channels

// async global->LDS, 16B per lane; LDS dest is wave-uniform base + lane*16
#define GLD16(g, l) __builtin_amdgcn_global_load_lds( \
    (const __attribute__((address_space(1))) unsigned int*)(const void*)(g), \
    (__attribute__((address_space(3))) unsigned int*)(void*)(l), 16, 0, 0)

// ---------------------------------------------------------------------------
// Fused prelude: blocks [0,2048) run KNN v9; blocks [2048,4864) run prep.
// KNN v9 = v8 selection logic with a PERSISTENT p2 table: |p|^2 computed
// once into LDS (skewed, conflict-free); pass 1 reads xyz directly from
// global (float4, 16-lane broadcast, L2-resident — pass-2's proven pattern)
// and p2 from LDS. No candidate restaging, no per-chunk barriers. All
// distance expressions are the identical source strings as v8 -> gate,
// survivor set, and output bit-identical.
// ---------------------------------------------------------------------------
#define KQ     16
#define KSEG   16
#define KCH    64
#define KSTAGE 1024
#define KRING  96

__global__ __launch_bounds__(256)
void pre_kernel(const float* __restrict__ pcA, const float* __restrict__ pcB,
                int* __restrict__ idxAB, int* __restrict__ idxBA,
                const float* __restrict__ feat1, const float* __restrict__ feat2,
                float* __restrict__ p1pm, bf16* __restrict__ p1b,
                float* __restrict__ p2pm, bf16* __restrict__ p2b,
                const float* __restrict__ lin1_w, bf16* __restrict__ b1hi, bf16* __restrict__ b1lo,
                const float* __restrict__ lin2_w, bf16* __restrict__ b2hi, bf16* __restrict__ b2lo)
{
    __shared__ float  p2s[NPT + 256];              // skew: +4 words per 64
    __shared__ float  pubd[2][KSEG][KQ];
    __shared__ float4 qc[KQ];
    __shared__ float  u16s[KQ];
    __shared__ int    rcnt[KQ];
    __shared__ int    wtot;
    __shared__ int    wl[256];
    __shared__ float  ringd[KQ][KRING + 1];
    __shared__ int    ringi[KQ][KRING + 1];
    __shared__ float  t[32][33];

    const int bid = blockIdx.x;
    const int tid = threadIdx.x;

    if (bid < 2048) {
        // =================== KNN v9 ===================
        const int dir = bid >> 10;
        const int b   = (bid >> 8) & 3;
        const int g   = bid & 255;
        const float* qxyz = dir ? pcB : pcA;
        const float* cxyz = dir ? pcA : pcB;
        int* idx_out      = dir ? idxBA : idxAB;

        const int q = tid & (KQ - 1);
        const int s = tid >> 4;
        const int n = g * KQ + q;

        const float* qp = qxyz + (size_t)b * 3 * NPT;
        const float qx = qp[n], qy = qp[NPT + n], qz = qp[2 * NPT + n];
        const float q2 = fmaf(qx, qx, fmaf(qy, qy, qz * qz));
        const float* c = cxyz + (size_t)b * 3 * NPT;

        if (tid < KQ) rcnt[tid] = 0;
        if (tid == 0) wtot = 0;
        if (s == 0) qc[q] = make_float4(qx, qy, qz, q2);

        // ---- build persistent |p|^2 table (once) ----
        #pragma unroll
        for (int r = 0; r < NPT / 256; ++r) {
            const int j = r * 256 + tid;
            const float x = c[j], y = c[NPT + j], z = c[2 * NPT + j];
            p2s[j + ((j >> 6) << 2)] = fmaf(x, x, fmaf(y, y, z * z));
        }
        __syncthreads();

        // ---- pass 1: min(+argmin) and 2nd-smallest per (q,s), direct xyz ----
        float b0 = 3.4e38f, b1 = 3.4e38f;
        int   i0 = 0;
        #pragma unroll 1
        for (int ch = 0; ch < 4; ++ch) {
            const int segbase = ch * KSTAGE + s * KCH;
            #pragma unroll 4
            for (int jj = 0; jj < KCH; jj += 4) {
                const int j = segbase + jj;
                const float4 xs = *(const float4*)(c + j);
                const float4 ys = *(const float4*)(c + NPT + j);
                const float4 zs = *(const float4*)(c + 2 * NPT + j);
                const float4 ps = *(const float4*)&p2s[j + ((j >> 6) << 2)];
                const float xv[4] = { xs.x, xs.y, xs.z, xs.w };
                const float yv[4] = { ys.x, ys.y, ys.z, ys.w };
                const float zv[4] = { zs.x, zs.y, zs.z, zs.w };
                const float pv[4] = { ps.x, ps.y, ps.z, ps.w };
                #pragma unroll
                for (int e = 0; e < 4; ++e) {
                    const float dot = fmaf(qx, xv[e], fmaf(qy, yv[e], qz * zv[e]));
                    const float d = q2 + pv[e] - 2.f * dot;
                    i0 = (d < b0) ? (j + e) : i0;
                    const float tt = fmaxf(b0, d);
                    b0 = fminf(b0, d);
                    b1 = fminf(b1, tt);
                }
            }
        }
        pubd[0][s][q] = b0;
        pubd[1][s][q] = b1;
        __syncthreads();

        // ---- u16: 16th smallest of 32 published values (rank == 15) ----
        {
            float tv[32];
            #pragma unroll
            for (int j = 0; j < 32; ++j) tv[j] = pubd[j >> 4][j & 15][q];
            #pragma unroll
            for (int rep = 0; rep < 2; ++rep) {
                const int j = rep * 16 + s;
                const float vj = pubd[rep][s][q];
                int rank = 0;
                #pragma unroll
                for (int k = 0; k < 32; ++k)
                    rank += (tv[k] < vj || (tv[k] == vj && k < j)) ? 1 : 0;
                if (rank == 15) u16s[q] = vj;
            }
        }
        __syncthreads();

        // ---- classify: direct-append single-survivor segments; rest rescan ----
        {
            const float gate = u16s[q];
            if (b0 <= gate) {
                if (b1 > gate) {
                    const int slot = atomicAdd(&rcnt[q], 1);
                    if (slot < KRING) { ringd[q][slot] = b0; ringi[q][slot] = i0; }
                } else {
                    const int u = atomicAdd(&wtot, 1);
                    wl[u] = (q << 4) | s;
                }
            }
        }
        __syncthreads();

        // ---- pass 2: cooperative rescan of multi-survivor segments ----
        {
            const int W = wtot;
            const int lu = tid & 15;
            for (int u = tid >> 4; u < W; u += 16) {
                const int qq  = wl[u] >> 4;
                const int seg = wl[u] & 15;
                const float4 qv = qc[qq];
                const float gate = u16s[qq];
                #pragma unroll
                for (int ch = 0; ch < 4; ++ch) {
                    const int j = ch * KSTAGE + seg * KCH + lu * 4;
                    const float4 xs = *(const float4*)(c + j);
                    const float4 ys = *(const float4*)(c + NPT + j);
                    const float4 zs = *(const float4*)(c + 2 * NPT + j);
                    const float xv[4] = { xs.x, xs.y, xs.z, xs.w };
                    const float yv[4] = { ys.x, ys.y, ys.z, ys.w };
                    const float zv[4] = { zs.x, zs.y, zs.z, zs.w };
                    #pragma unroll
                    for (int e = 0; e < 4; ++e) {
                        const float p2 = fmaf(xv[e], xv[e], fmaf(yv[e], yv[e], zv[e] * zv[e]));
                        const float dot = fmaf(qv.x, xv[e], fmaf(qv.y, yv[e], qv.z * zv[e]));
                        const float d = qv.w + p2 - 2.f * dot;
                        if (d <= gate) {
                            const int slot = atomicAdd(&rcnt[qq], 1);
                            if (slot < KRING) { ringd[qq][slot] = d; ringi[qq][slot] = j + e; }
                        }
                    }
                }
            }
        }
        __syncthreads();

        // ---- final: exact (d, idx) rank-select of top-16 from the ring ----
        {
            const int cnt = min(rcnt[q], KRING);
            int* op = idx_out + ((size_t)b * NPT + n) * NBR;
            for (int e = s; e < cnt; e += KSEG) {
                const float de = ringd[q][e];
                const int   ie = ringi[q][e];
                int rank = 0;
                for (int k = 0; k < cnt; ++k) {
                    const float dk = ringd[q][k];
                    const int   ik = ringi[q][k];
                    rank += (dk < de || (dk == de && ik < ie)) ? 1 : 0;
                }
                if (rank < NBR) op[rank] = ie;
            }
        }
    } else {
        // =================== prep ===================
        const int tx = tid & 31, ty = tid >> 5;
        const int id = bid - 2048;
        if (id < 2048) {
            const int which = id >> 10;
            const int nt = id & 1023;
            const int n0 = (nt & 127) * 32;
            const int c0 = ((nt >> 7) & 1) * 32;
            const int b  = nt >> 8;
            const float* in = which ? feat2 : feat1;
            float* out  = which ? p2pm : p1pm;
            bf16*  outb = which ? p2b  : p1b;
            #pragma unroll
            for (int r = ty; r < 32; r += 8)
                t[r][tx] = in[((size_t)b * CDIM + c0 + r) * NPT + n0 + tx];
            __syncthreads();
            #pragma unroll
            for (int r = ty; r < 32; r += 8) {
                const float v = t[tx][r];
                out [((size_t)b * NPT + n0 + r) * CDIM + c0 + tx] = v;
                outb[((size_t)b * NPT + n0 + r) * CDIM + c0 + tx] = __float2bfloat16(v);
            }
        } else {
            const float* w; bf16 *hi, *lo; int K, k0, o0;
            if (id < 2304) {
                const int id2 = id - 2048;
                w = lin1_w; hi = b1hi; lo = b1lo; K = 2048;
                k0 = (id2 & 63) * 32; o0 = (id2 >> 6) * 32;
            } else {
                const int id2 = id - 2304;
                w = lin2_w; hi = b2hi; lo = b2lo; K = 4096;
                k0 = (id2 & 127) * 32; o0 = (id2 >> 7) * 32;
            }
            #pragma unroll
            for (int r = ty; r < 32; r += 8)
                t[r][tx] = w[(size_t)(k0 + r) * MIDD + o0 + tx];
            __syncthreads();
            #pragma unroll
            for (int r = ty; r < 32; r += 8) {
                const float v = t[tx][r];
                const bf16 h = __float2bfloat16(v);
                const bf16 l2 = __float2bfloat16(v - __bfloat162float(h));
                hi[(size_t)(o0 + r) * K + k0 + tx] = h;
                lo[(size_t)(o0 + r) * K + k0 + tx] = l2;
            }
        }
    }
}

// ---------------------------------------------------------------------------
// Weightnet + aggregation v8 (round-22, unchanged): row-sharing thread map.
// ---------------------------------------------------------------------------
template<int D2, int PTS>
__global__ __launch_bounds__(256)
void agg_kernel(const float* __restrict__ qA, const float* __restrict__ cA,
                const bf16* __restrict__ nbrA, const int* __restrict__ idxA,
                const float* __restrict__ qB, const float* __restrict__ cB,
                const bf16* __restrict__ nbrB, const int* __restrict__ idxB,
                int Msplit,
                const float* __restrict__ w0, const float* __restrict__ b0,
                const float* __restrict__ w1, const float* __restrict__ b1,
                const float* __restrict__ w2, const float* __restrict__ b2,
                bf16* __restrict__ agg, float* __restrict__ swb, int m0)
{
    constexpr int TPP  = 256 / PTS;
    constexpr int ND   = D2 / TPP;      // 2
    constexpr int WSTR = 276;

    __shared__ float wp[248];
    __shared__ int   nb[PTS * NBR];
    __shared__ float wgt[PTS * WSTR];

    const int tid = threadIdx.x;
    const int mbase = m0 + (int)blockIdx.x * PTS;
    const bool second = mbase >= Msplit;
    const int mrow = second ? mbase - Msplit : mbase;
    const float* qxyz   = second ? qB   : qA;
    const float* cxyz   = second ? cB   : cA;
    const bf16*  nbr_b  = second ? nbrB : nbrA;
    const int*   idx    = second ? idxB : idxA;
    const int b = mrow >> 12;
    const int nbase = mrow & (NPT - 1);

    if (tid < 248) {
        float v;
        if      (tid <  24) v = w0[tid];
        else if (tid <  32) v = b0[tid - 24];
        else if (tid <  96) v = w1[tid - 32];
        else if (tid < 104) v = b1[tid - 96];
        else if (tid < 232) v = w2[tid - 104];
        else                v = b2[tid - 232];
        wp[tid] = v;
    }
    if (tid < PTS * NBR)
        nb[tid] = idx[(size_t)mrow * NBR + tid];
    __syncthreads();

    const int p  = tid / TPP;
    const int dg = tid % TPP;
    const int d0 = dg * ND;

    unsigned int F[NBR];
    {
        const bf16* base = nbr_b + (size_t)b * NPT * D2 + d0;
        #pragma unroll
        for (int k = 0; k < NBR; ++k) {
            const int j = nb[p * NBR + k];
            F[k] = *(const unsigned int*)(base + (size_t)j * D2);
        }
    }

    if (tid < PTS * NBR) {
        const int pp = tid / NBR, k = tid % NBR;
        const int n = nbase + pp;
        const int j = nb[tid];
        const float* q = qxyz + (size_t)b * 3 * NPT;
        const float* c = cxyz + (size_t)b * 3 * NPT;
        const float dx = c[j]           - q[n];
        const float dy = c[NPT + j]     - q[NPT + n];
        const float dz = c[2 * NPT + j] - q[2 * NPT + n];
        float h1[8], h2[8];
        #pragma unroll
        for (int o = 0; o < 8; ++o) {
            float v = wp[24 + o];
            v = fmaf(dx, wp[o], v);
            v = fmaf(dy, wp[8 + o], v);
            v = fmaf(dz, wp[16 + o], v);
            h1[o] = fmaxf(v, 0.f);
        }
        #pragma unroll
        for (int o = 0; o < 8; ++o) {
            float v = wp[96 + o];
            #pragma unroll
            for (int i = 0; i < 8; ++i) v = fmaf(h1[i], wp[32 + i * 8 + o], v);
            h2[o] = fmaxf(v, 0.f);
        }
        #pragma unroll
        for (int o = 0; o < WD; ++o) {
            float v = wp[232 + o];
            #pragma unroll
            for (int i = 0; i < 8; ++i) v = fmaf(h2[i], wp[104 + i * WD + o], v);
            wgt[pp * WSTR + k * WD + o] = fmaxf(v, 0.f);
        }
    }
    __syncthreads();

    if (tid < PTS * 16) {
        const int pp = tid >> 4, w = tid & 15;
        const float* wgp = wgt + pp * WSTR + w;
        float sv = 0.f;
        #pragma unroll
        for (int k = 0; k < NBR; ++k) sv += wgp[k * WD];
        swb[(size_t)((int)blockIdx.x * PTS + pp) * 16 + w] = sv;
    }

    {
        const float* wg = wgt + p * WSTR;
        bf16* aout = agg + ((size_t)((int)blockIdx.x * PTS + p)) * (2 * D2 * WD);
        float acc[ND][16];
        #pragma unroll
        for (int di = 0; di < ND; ++di)
            #pragma unroll
            for (int w = 0; w < 16; ++w) acc[di][w] = 0.f;
        #pragma unroll
        for (int k = 0; k < NBR; ++k) {
            union { unsigned int u; bf16 h[2]; } uf;
            uf.u = F[k];
            float Fv[ND];
            #pragma unroll
            for (int j = 0; j < ND; ++j) Fv[j] = __bfloat162float(uf.h[j]);
            const float4 v0 = *(const float4*)(wg + k * WD);
            const float4 v1 = *(const float4*)(wg + k * WD + 4);
            const float4 v2 = *(const float4*)(wg + k * WD + 8);
            const float4 v3 = *(const float4*)(wg + k * WD + 12);
            float w16[16];
            w16[0]  = v0.x; w16[1]  = v0.y; w16[2]  = v0.z; w16[3]  = v0.w;
            w16[4]  = v1.x; w16[5]  = v1.y; w16[6]  = v1.z; w16[7]  = v1.w;
            w16[8]  = v2.x; w16[9]  = v2.y; w16[10] = v2.z; w16[11] = v2.w;
            w16[12] = v3.x; w16[13] = v3.y; w16[14] = v3.z; w16[15] = v3.w;
            #pragma unroll
            for (int di = 0; di < ND; ++di)
                #pragma unroll
                for (int w = 0; w < 16; ++w)
                    acc[di][w] = fmaf(Fv[di], w16[w], acc[di][w]);
        }
        #pragma unroll
        for (int di = 0; di < ND; ++di) {
            union { bf16 h[16]; uint4 q[2]; } pk;
            #pragma unroll
            for (int w = 0; w < 16; ++w) pk.h[w] = __float2bfloat16(acc[di][w]);
            bf16* dst = aout + (D2 + d0 + di) * WD;
            *(uint4*)dst       = pk.q[0];
            *(uint4*)(dst + 8) = pk.q[1];
        }
    }
}

// ---------------------------------------------------------------------------
// MFMA GEMM k64 (round-21 structure) + split epilogue: fpm (f32 pm) written
// only for rows < Msplit (cross-3 own-half source); fb (bf16 pm) only for
// rows >= Msplit (cross-3 gather source). The skipped halves were never read.
// ---------------------------------------------------------------------------
template<int BM>
__global__ __launch_bounds__(256)
void gemm_mfma_k64(const bf16* __restrict__ A, const bf16* __restrict__ Bhi,
                   const bf16* __restrict__ Blo, const float* __restrict__ bias,
                   const float* __restrict__ ownf, const float* __restrict__ swb,
                   float* __restrict__ out_t, float* __restrict__ out_pm,
                   bf16* __restrict__ out_pmb, int Msplit, int m0, int K)
{
    constexpr int AE   = BM * 64;
    constexpr int BT   = 128 * 64;
    constexpr int BUFE = AE + 2 * BT;
    constexpr int MF   = BM / 32;
    constexpr int RA   = BM * 8 / 256;
    __shared__ __align__(16) char smem[2 * BUFE * 2];
    bf16* lds = (bf16*)smem;

    const int tid  = threadIdx.x;
    const int w    = tid >> 6;
    const int lane = tid & 63;
    const int wr   = w >> 1, wc = w & 1;
    const int mb   = (int)blockIdx.x * BM;
    const int gK   = lane >> 4;
    const int rL   = lane & 15;
    const int D2v  = K / 32;

    int rowA[RA], schA[RA];
    float sww[RA][8];
    const float* ownrow_g[RA];
    #pragma unroll
    for (int r = 0; r < RA; ++r) {
        const int slot = r * 256 + tid;
        rowA[r] = slot >> 3;
        const int ch = slot & 7;
        schA[r] = ch ^ (rowA[r] & 7);
        const int w0 = (schA[r] & 1) * 8;
        const float* sp = swb + (size_t)(mb + rowA[r]) * 16 + w0;
        const float4 a = *(const float4*)sp;
        const float4 b2 = *(const float4*)(sp + 4);
        sww[r][0] = a.x;  sww[r][1] = a.y;  sww[r][2] = a.z;  sww[r][3] = a.w;
        sww[r][4] = b2.x; sww[r][5] = b2.y; sww[r][6] = b2.z; sww[r][7] = b2.w;
        ownrow_g[r] = ownf + (size_t)(m0 + mb + rowA[r]) * D2v;
    }

    f32x4 acc[MF][4];
    #pragma unroll
    for (int i = 0; i < MF; ++i)
        #pragma unroll
        for (int j = 0; j < 4; ++j) acc[i][j] = (f32x4)0.f;

    const int nk = K / 64;
    const int nkOwn = nk / 2;

    auto stage = [&](int buf, int kt) {
        const int kb = kt * 64;
        const int bufo = buf * BUFE;
        if (kt < nkOwn) {
            #pragma unroll
            for (int r = 0; r < RA; ++r) {
                const int d = kt * 4 + (schA[r] >> 1);
                const float f = ownrow_g[r][d];
                union { bf16 h[8]; uint4 q; } pk;
                #pragma unroll
                for (int j = 0; j < 8; ++j) pk.h[j] = __float2bfloat16(f * sww[r][j]);
                *(uint4*)(lds + bufo + (r * 256 + tid) * 8) = pk.q;
            }
        } else {
            #pragma unroll
            for (int r = 0; r < RA; ++r)
                GLD16(A + (size_t)(mb + rowA[r]) * K + kb + (schA[r] << 3),
                      lds + bufo + ((r * 256 + w * 64) << 3));
        }
        #pragma unroll
        for (int i = 0; i < 4; ++i) {
            const int s2 = i * 256 + tid;
            const int row = s2 >> 3, ch = s2 & 7;
            const int sch = ch ^ (row & 7);
            const int wb = (i * 256 + w * 64) << 3;
            GLD16(Bhi + (size_t)row * K + kb + (sch << 3), lds + bufo + AE + wb);
            GLD16(Blo + (size_t)row * K + kb + (sch << 3), lds + bufo + AE + BT + wb);
        }
    };

    stage(0, 0);
    __syncthreads();

    for (int kt = 0; kt < nk; ++kt) {
        const int cur = kt & 1;
        if (kt + 1 < nk) stage(cur ^ 1, kt + 1);

        const bf16* la  = lds + cur * BUFE;
        const bf16* lbh = la + AE;
        const bf16* lbl = la + AE + BT;

        #pragma unroll
        for (int kk2 = 0; kk2 < 2; ++kk2) {
            const int cc = gK + kk2 * 4;
            bf16x8 af[MF], bh[4], bl[4];
            #pragma unroll
            for (int mf = 0; mf < MF; ++mf) {
                const int row = wr * (BM / 2) + mf * 16 + rL;
                af[mf] = *(const bf16x8*)(la + row * 64 + ((cc ^ (row & 7)) << 3));
            }
            #pragma unroll
            for (int nf = 0; nf < 4; ++nf) {
                const int col = wc * 64 + nf * 16 + rL;
                const int off = col * 64 + ((cc ^ (col & 7)) << 3);
                bh[nf] = *(const bf16x8*)(lbh + off);
                bl[nf] = *(const bf16x8*)(lbl + off);
            }
            #pragma unroll
            for (int mf = 0; mf < MF; ++mf)
                #pragma unroll
                for (int nf = 0; nf < 4; ++nf) {
                    acc[mf][nf] = __builtin_amdgcn_mfma_f32_16x16x32_bf16(af[mf], bh[nf], acc[mf][nf], 0, 0, 0);
                    acc[mf][nf] = __builtin_amdgcn_mfma_f32_16x16x32_bf16(af[mf], bl[nf], acc[mf][nf], 0, 0, 0);
                }
        }
        __syncthreads();
    }

    float (*tile)[133] = (float(*)[133])smem;
    #pragma unroll
    for (int mf = 0; mf < MF; ++mf)
        #pragma unroll
        for (int nf = 0; nf < 4; ++nf) {
            const int col = wc * 64 + nf * 16 + rL;
            const float bs = bias[col];
            #pragma unroll
            for (int qq = 0; qq < 4; ++qq) {
                const int rrow = wr * (BM / 2) + mf * 16 + gK * 4 + qq;
                const float v = acc[mf][nf][qq] + bs;
                tile[rrow][col] = v > 0.f ? v : 0.1f * v;
            }
        }
    __syncthreads();

    const int mrow = m0 + mb;
    const int b = mrow >> 12, n0 = mrow & (NPT - 1);
    for (int e = tid; e < BM * MIDD; e += 256) {
        const int o = e / BM, i = e % BM;
        out_t[((size_t)b * MIDD + o) * NPT + n0 + i] = tile[i][o];
    }
    if (out_pm && mrow < Msplit) {          // f1 side: f32 pm (cross-3 own)
        for (int e = tid; e < BM * MIDD; e += 256) {
            const int i = e >> 7, o = e & 127;
            out_pm[(size_t)(mrow + i) * MIDD + o] = tile[i][o];
        }
    }
    if (out_pmb && mrow >= Msplit) {        // f2 side: bf16 pm (cross-3 gather)
        for (int e = tid; e < BM * MIDD; e += 256) {
            const int i = e >> 7, o = e & 127;
            out_pmb[(size_t)(mrow + i) * MIDD + o] = __float2bfloat16(tile[i][o]);
        }
    }
}

// ---------------------------------------------------------------------------
extern "C" void kernel_launch(void* const* d_in, const int* in_sizes, int n_in,
                              void* d_out, int out_size, void* d_ws, size_t ws_size,
                              hipStream_t stream)
{
    (void)in_sizes; (void)n_in; (void)out_size;
    const float* pc1    = (const float*)d_in[0];
    const float* pc2    = (const float*)d_in[1];
    const float* feat1  = (const float*)d_in[2];
    const float* feat2  = (const float*)d_in[3];
    const float* wn1_w0 = (const float*)d_in[4];
    const float* wn1_b0 = (const float*)d_in[5];
    const float* wn1_w1 = (const float*)d_in[6];
    const float* wn1_b1 = (const float*)d_in[7];
    const float* wn1_w2 = (const float*)d_in[8];
    const float* wn1_b2 = (const float*)d_in[9];
    const float* lin1_w = (const float*)d_in[10];
    const float* lin1_b = (const float*)d_in[11];
    const float* wn2_w0 = (const float*)d_in[12];
    const float* wn2_b0 = (const float*)d_in[13];
    const float* wn2_w1 = (const float*)d_in[14];
    const float* wn2_b1 = (const float*)d_in[15];
    const float* wn2_w2 = (const float*)d_in[16];
    const float* wn2_b2 = (const float*)d_in[17];
    const float* lin2_w = (const float*)d_in[18];
    const float* lin2_b = (const float*)d_in[19];
    float* out = (float*)d_out;

    const int M  = BB * NPT;
    const int M2 = 2 * M;
    const int K1 = 2 * CDIM * WD;     // 2048
    const int K2 = 2 * MIDD * WD;     // 4096

    char* ws = (char*)d_ws;
    float* p1pm = (float*)ws;
    float* p2pm = p1pm + (size_t)M * CDIM;
    float* fpm  = p2pm + (size_t)M * CDIM;
    bf16*  p1b  = (bf16*)(fpm + (size_t)M2 * MIDD);
    bf16*  p2b  = p1b + (size_t)M * CDIM;
    bf16*  fb   = p2b + (size_t)M * CDIM;
    int* idx12  = (int*)(fb + (size_t)M2 * MIDD);
    int* idx21  = idx12 + (size_t)M * NBR;
    bf16* b1hi  = (bf16*)(idx21 + (size_t)M * NBR);
    bf16* b1lo  = b1hi + (size_t)MIDD * K1;
    bf16* b2hi  = b1lo + (size_t)MIDD * K1;
    bf16* b2lo  = b2hi + (size_t)MIDD * K2;
    float* swbuf = (float*)(b2lo + (size_t)MIDD * K2);
    bf16* aggbuf = (bf16*)(swbuf + (size_t)(M2 + 64) * 16);
    const size_t used = (size_t)((char*)aggbuf - ws);
    const size_t avail = ws_size > used ? ws_size - used : 0;

    float* f1t = out;
    float* fft = out + 2 * (size_t)BB * MIDD * NPT;

    pre_kernel<<<2048 + 2816, 256, 0, stream>>>(
        pc1, pc2, idx12, idx21,
        feat1, feat2, p1pm, p1b, p2pm, p2b,
        lin1_w, b1hi, b1lo, lin2_w, b2hi, b2lo);

    auto chunk_rows = [&](int K) -> int {
        long rows = (long)(avail / ((size_t)K * sizeof(bf16)));
        int cm = (int)(rows > M2 ? M2 : rows) & ~127;
        if (cm < 128) cm = 128;
        return cm;
    };

    {   // cross 1 + cross 2 merged (K = 2048); BM=64, BK=64
        const int CMr = chunk_rows(K1);
        for (int m0 = 0; m0 < M2; m0 += CMr) {
            const int cm = (M2 - m0 < CMr) ? (M2 - m0) : CMr;
            agg_kernel<CDIM, 8><<<cm / 8, 256, 0, stream>>>(
                pc1, pc2, p2b, idx12,
                pc2, pc1, p1b, idx21, M,
                wn1_w0, wn1_b0, wn1_w1, wn1_b1, wn1_w2, wn1_b2,
                aggbuf, swbuf, m0);
            gemm_mfma_k64<64><<<cm / 64, 256, 0, stream>>>(aggbuf, b1hi, b1lo, lin1_b,
                                                           p1pm, swbuf,
                                                           f1t, fpm, fb, M, m0, K1);
        }
    }
    {   // cross 3 (K = 4096); BM=32, BK=64
        const int CMr = chunk_rows(K2);
        for (int m0 = 0; m0 < M; m0 += CMr) {
            const int cm = (M - m0 < CMr) ? (M - m0) : CMr;
            agg_kernel<MIDD, 4><<<cm / 4, 256, 0, stream>>>(
                pc1, pc2, fb + (size_t)M * MIDD, idx12,
                nullptr, nullptr, nullptr, nullptr, M2,
                wn2_w0, wn2_b0, wn2_w1, wn2_b1, wn2_w2, wn2_b2,
                aggbuf, swbuf, m0);
            gemm_mfma_k64<32><<<cm / 32, 256, 0, stream>>>(aggbuf, b2hi, b2lo, lin2_b,
                                                           fpm, swbuf,
                                                           fft, nullptr, nullptr, 0, m0, K2);
        }
    }
}

// Round 24
// 267.490 us; speedup vs baseline: 1.0442x; 1.0442x over previous
//
#include <hip/hip_runtime.h>
#include <hip/hip_bf16.h>
#include <cstddef>
#include <cstdint>

typedef __hip_bfloat16 bf16;
typedef __attribute__((ext_vector_type(8))) short bf16x8;   // 8 bf16 = 4 VGPRs
typedef __attribute__((ext_vector_type(4))) float f32x4;

#define NPT 4096   // points per cloud
#define BB  4      // batch
#define NBR 16     // neighbors (nsample)
#define WD  16     // weightnet output width
#define CDIM 64    // input feature channels
#define MIDD 128   // lin1/lin2 output channels

// async global->LDS, 16B per lane; LDS dest is wave-uniform base + lane*16
#define GLD16(g, l) __builtin_amdgcn_global_load_lds( \
    (const __attribute__((address_space(1))) unsigned int*)(const void*)(g), \
    (__attribute__((address_space(3))) unsigned int*)(void*)(l), 16, 0, 0)

// ---------------------------------------------------------------------------
// Fused prelude (round-22 version, restored): blocks [0,2048) run KNN v8
// (staged pass 1 — settled as faster than direct-global); [2048,4864) prep.
// ---------------------------------------------------------------------------
#define KQ     16
#define KSEG   16
#define KCH    64
#define KSTAGE 1024
#define KRING  96

__global__ __launch_bounds__(256)
void pre_kernel(const float* __restrict__ pcA, const float* __restrict__ pcB,
                int* __restrict__ idxAB, int* __restrict__ idxBA,
                const float* __restrict__ feat1, const float* __restrict__ feat2,
                float* __restrict__ p1pm, bf16* __restrict__ p1b,
                float* __restrict__ p2pm, bf16* __restrict__ p2b,
                const float* __restrict__ lin1_w, bf16* __restrict__ b1hi, bf16* __restrict__ b1lo,
                const float* __restrict__ lin2_w, bf16* __restrict__ b2hi, bf16* __restrict__ b2lo)
{
    __shared__ float4 cf[KSTAGE + KSTAGE / KCH];   // skewed
    __shared__ float  pubd[2][KSEG][KQ];
    __shared__ float4 qc[KQ];
    __shared__ float  u16s[KQ];
    __shared__ int    rcnt[KQ];
    __shared__ int    wtot;
    __shared__ int    wl[256];
    __shared__ float  ringd[KQ][KRING + 1];
    __shared__ int    ringi[KQ][KRING + 1];
    __shared__ float  t[32][33];

    const int bid = blockIdx.x;
    const int tid = threadIdx.x;

    if (bid < 2048) {
        // =================== KNN v8 ===================
        const int dir = bid >> 10;
        const int b   = (bid >> 8) & 3;
        const int g   = bid & 255;
        const float* qxyz = dir ? pcB : pcA;
        const float* cxyz = dir ? pcA : pcB;
        int* idx_out      = dir ? idxBA : idxAB;

        const int q = tid & (KQ - 1);
        const int s = tid >> 4;
        const int n = g * KQ + q;

        const float* qp = qxyz + (size_t)b * 3 * NPT;
        const float qx = qp[n], qy = qp[NPT + n], qz = qp[2 * NPT + n];
        const float q2 = fmaf(qx, qx, fmaf(qy, qy, qz * qz));
        const float* c = cxyz + (size_t)b * 3 * NPT;

        if (tid < KQ) rcnt[tid] = 0;
        if (tid == 0) wtot = 0;
        if (s == 0) qc[q] = make_float4(qx, qy, qz, q2);

        float b0 = 3.4e38f, b1 = 3.4e38f;
        int   i0 = 0;
        for (int st = 0; st < NPT; st += KSTAGE) {
            __syncthreads();
            {
                #pragma unroll
                for (int r = 0; r < KSTAGE / 256; ++r) {
                    const int j = r * 256 + tid;
                    const int gg = st + j;
                    const float x = c[gg], y = c[NPT + gg], z = c[2 * NPT + gg];
                    cf[j + (j >> 6)] = make_float4(x, y, z,
                        fmaf(x, x, fmaf(y, y, z * z)));
                }
            }
            __syncthreads();
            const int base = s * (KCH + 1);
            const int gidx = st + s * KCH;
            #pragma unroll 4
            for (int jj = 0; jj < KCH; ++jj) {
                const float4 pv = cf[base + jj];
                const float dot = fmaf(qx, pv.x, fmaf(qy, pv.y, qz * pv.z));
                const float d = q2 + pv.w - 2.f * dot;
                i0 = (d < b0) ? (gidx + jj) : i0;
                const float tt = fmaxf(b0, d);
                b0 = fminf(b0, d);
                b1 = fminf(b1, tt);
            }
        }
        pubd[0][s][q] = b0;
        pubd[1][s][q] = b1;
        __syncthreads();

        {
            float tv[32];
            #pragma unroll
            for (int j = 0; j < 32; ++j) tv[j] = pubd[j >> 4][j & 15][q];
            #pragma unroll
            for (int rep = 0; rep < 2; ++rep) {
                const int j = rep * 16 + s;
                const float vj = pubd[rep][s][q];
                int rank = 0;
                #pragma unroll
                for (int k = 0; k < 32; ++k)
                    rank += (tv[k] < vj || (tv[k] == vj && k < j)) ? 1 : 0;
                if (rank == 15) u16s[q] = vj;
            }
        }
        __syncthreads();

        {
            const float gate = u16s[q];
            if (b0 <= gate) {
                if (b1 > gate) {
                    const int slot = atomicAdd(&rcnt[q], 1);
                    if (slot < KRING) { ringd[q][slot] = b0; ringi[q][slot] = i0; }
                } else {
                    const int u = atomicAdd(&wtot, 1);
                    wl[u] = (q << 4) | s;
                }
            }
        }
        __syncthreads();

        {
            const int W = wtot;
            const int lu = tid & 15;
            for (int u = tid >> 4; u < W; u += 16) {
                const int qq  = wl[u] >> 4;
                const int seg = wl[u] & 15;
                const float4 qv = qc[qq];
                const float gate = u16s[qq];
                #pragma unroll
                for (int ch = 0; ch < 4; ++ch) {
                    const int j = ch * KSTAGE + seg * KCH + lu * 4;
                    const float4 xs = *(const float4*)(c + j);
                    const float4 ys = *(const float4*)(c + NPT + j);
                    const float4 zs = *(const float4*)(c + 2 * NPT + j);
                    const float xv[4] = { xs.x, xs.y, xs.z, xs.w };
                    const float yv[4] = { ys.x, ys.y, ys.z, ys.w };
                    const float zv[4] = { zs.x, zs.y, zs.z, zs.w };
                    #pragma unroll
                    for (int e = 0; e < 4; ++e) {
                        const float p2 = fmaf(xv[e], xv[e], fmaf(yv[e], yv[e], zv[e] * zv[e]));
                        const float dot = fmaf(qv.x, xv[e], fmaf(qv.y, yv[e], qv.z * zv[e]));
                        const float d = qv.w + p2 - 2.f * dot;
                        if (d <= gate) {
                            const int slot = atomicAdd(&rcnt[qq], 1);
                            if (slot < KRING) { ringd[qq][slot] = d; ringi[qq][slot] = j + e; }
                        }
                    }
                }
            }
        }
        __syncthreads();

        {
            const int cnt = min(rcnt[q], KRING);
            int* op = idx_out + ((size_t)b * NPT + n) * NBR;
            for (int e = s; e < cnt; e += KSEG) {
                const float de = ringd[q][e];
                const int   ie = ringi[q][e];
                int rank = 0;
                for (int k = 0; k < cnt; ++k) {
                    const float dk = ringd[q][k];
                    const int   ik = ringi[q][k];
                    rank += (dk < de || (dk == de && ik < ie)) ? 1 : 0;
                }
                if (rank < NBR) op[rank] = ie;
            }
        }
    } else {
        // =================== prep ===================
        const int tx = tid & 31, ty = tid >> 5;
        const int id = bid - 2048;
        if (id < 2048) {
            const int which = id >> 10;
            const int nt = id & 1023;
            const int n0 = (nt & 127) * 32;
            const int c0 = ((nt >> 7) & 1) * 32;
            const int b  = nt >> 8;
            const float* in = which ? feat2 : feat1;
            float* out  = which ? p2pm : p1pm;
            bf16*  outb = which ? p2b  : p1b;
            #pragma unroll
            for (int r = ty; r < 32; r += 8)
                t[r][tx] = in[((size_t)b * CDIM + c0 + r) * NPT + n0 + tx];
            __syncthreads();
            #pragma unroll
            for (int r = ty; r < 32; r += 8) {
                const float v = t[tx][r];
                out [((size_t)b * NPT + n0 + r) * CDIM + c0 + tx] = v;
                outb[((size_t)b * NPT + n0 + r) * CDIM + c0 + tx] = __float2bfloat16(v);
            }
        } else {
            const float* w; bf16 *hi, *lo; int K, k0, o0;
            if (id < 2304) {
                const int id2 = id - 2048;
                w = lin1_w; hi = b1hi; lo = b1lo; K = 2048;
                k0 = (id2 & 63) * 32; o0 = (id2 >> 6) * 32;
            } else {
                const int id2 = id - 2304;
                w = lin2_w; hi = b2hi; lo = b2lo; K = 4096;
                k0 = (id2 & 127) * 32; o0 = (id2 >> 7) * 32;
            }
            #pragma unroll
            for (int r = ty; r < 32; r += 8)
                t[r][tx] = w[(size_t)(k0 + r) * MIDD + o0 + tx];
            __syncthreads();
            #pragma unroll
            for (int r = ty; r < 32; r += 8) {
                const float v = t[tx][r];
                const bf16 h = __float2bfloat16(v);
                const bf16 l2 = __float2bfloat16(v - __bfloat162float(h));
                hi[(size_t)(o0 + r) * K + k0 + tx] = h;
                lo[(size_t)(o0 + r) * K + k0 + tx] = l2;
            }
        }
    }
}

// ---------------------------------------------------------------------------
// Weightnet + aggregation v8 (round-22, unchanged): row-sharing thread map.
// ---------------------------------------------------------------------------
template<int D2, int PTS>
__global__ __launch_bounds__(256)
void agg_kernel(const float* __restrict__ qA, const float* __restrict__ cA,
                const bf16* __restrict__ nbrA, const int* __restrict__ idxA,
                const float* __restrict__ qB, const float* __restrict__ cB,
                const bf16* __restrict__ nbrB, const int* __restrict__ idxB,
                int Msplit,
                const float* __restrict__ w0, const float* __restrict__ b0,
                const float* __restrict__ w1, const float* __restrict__ b1,
                const float* __restrict__ w2, const float* __restrict__ b2,
                bf16* __restrict__ agg, float* __restrict__ swb, int m0)
{
    constexpr int TPP  = 256 / PTS;
    constexpr int ND   = D2 / TPP;      // 2
    constexpr int WSTR = 276;

    __shared__ float wp[248];
    __shared__ int   nb[PTS * NBR];
    __shared__ float wgt[PTS * WSTR];

    const int tid = threadIdx.x;
    const int mbase = m0 + (int)blockIdx.x * PTS;
    const bool second = mbase >= Msplit;
    const int mrow = second ? mbase - Msplit : mbase;
    const float* qxyz   = second ? qB   : qA;
    const float* cxyz   = second ? cB   : cA;
    const bf16*  nbr_b  = second ? nbrB : nbrA;
    const int*   idx    = second ? idxB : idxA;
    const int b = mrow >> 12;
    const int nbase = mrow & (NPT - 1);

    if (tid < 248) {
        float v;
        if      (tid <  24) v = w0[tid];
        else if (tid <  32) v = b0[tid - 24];
        else if (tid <  96) v = w1[tid - 32];
        else if (tid < 104) v = b1[tid - 96];
        else if (tid < 232) v = w2[tid - 104];
        else                v = b2[tid - 232];
        wp[tid] = v;
    }
    if (tid < PTS * NBR)
        nb[tid] = idx[(size_t)mrow * NBR + tid];
    __syncthreads();

    const int p  = tid / TPP;
    const int dg = tid % TPP;
    const int d0 = dg * ND;

    unsigned int F[NBR];
    {
        const bf16* base = nbr_b + (size_t)b * NPT * D2 + d0;
        #pragma unroll
        for (int k = 0; k < NBR; ++k) {
            const int j = nb[p * NBR + k];
            F[k] = *(const unsigned int*)(base + (size_t)j * D2);
        }
    }

    if (tid < PTS * NBR) {
        const int pp = tid / NBR, k = tid % NBR;
        const int n = nbase + pp;
        const int j = nb[tid];
        const float* q = qxyz + (size_t)b * 3 * NPT;
        const float* c = cxyz + (size_t)b * 3 * NPT;
        const float dx = c[j]           - q[n];
        const float dy = c[NPT + j]     - q[NPT + n];
        const float dz = c[2 * NPT + j] - q[2 * NPT + n];
        float h1[8], h2[8];
        #pragma unroll
        for (int o = 0; o < 8; ++o) {
            float v = wp[24 + o];
            v = fmaf(dx, wp[o], v);
            v = fmaf(dy, wp[8 + o], v);
            v = fmaf(dz, wp[16 + o], v);
            h1[o] = fmaxf(v, 0.f);
        }
        #pragma unroll
        for (int o = 0; o < 8; ++o) {
            float v = wp[96 + o];
            #pragma unroll
            for (int i = 0; i < 8; ++i) v = fmaf(h1[i], wp[32 + i * 8 + o], v);
            h2[o] = fmaxf(v, 0.f);
        }
        #pragma unroll
        for (int o = 0; o < WD; ++o) {
            float v = wp[232 + o];
            #pragma unroll
            for (int i = 0; i < 8; ++i) v = fmaf(h2[i], wp[104 + i * WD + o], v);
            wgt[pp * WSTR + k * WD + o] = fmaxf(v, 0.f);
        }
    }
    __syncthreads();

    if (tid < PTS * 16) {
        const int pp = tid >> 4, w = tid & 15;
        const float* wgp = wgt + pp * WSTR + w;
        float sv = 0.f;
        #pragma unroll
        for (int k = 0; k < NBR; ++k) sv += wgp[k * WD];
        swb[(size_t)((int)blockIdx.x * PTS + pp) * 16 + w] = sv;
    }

    {
        const float* wg = wgt + p * WSTR;
        bf16* aout = agg + ((size_t)((int)blockIdx.x * PTS + p)) * (2 * D2 * WD);
        float acc[ND][16];
        #pragma unroll
        for (int di = 0; di < ND; ++di)
            #pragma unroll
            for (int w = 0; w < 16; ++w) acc[di][w] = 0.f;
        #pragma unroll
        for (int k = 0; k < NBR; ++k) {
            union { unsigned int u; bf16 h[2]; } uf;
            uf.u = F[k];
            float Fv[ND];
            #pragma unroll
            for (int j = 0; j < ND; ++j) Fv[j] = __bfloat162float(uf.h[j]);
            const float4 v0 = *(const float4*)(wg + k * WD);
            const float4 v1 = *(const float4*)(wg + k * WD + 4);
            const float4 v2 = *(const float4*)(wg + k * WD + 8);
            const float4 v3 = *(const float4*)(wg + k * WD + 12);
            float w16[16];
            w16[0]  = v0.x; w16[1]  = v0.y; w16[2]  = v0.z; w16[3]  = v0.w;
            w16[4]  = v1.x; w16[5]  = v1.y; w16[6]  = v1.z; w16[7]  = v1.w;
            w16[8]  = v2.x; w16[9]  = v2.y; w16[10] = v2.z; w16[11] = v2.w;
            w16[12] = v3.x; w16[13] = v3.y; w16[14] = v3.z; w16[15] = v3.w;
            #pragma unroll
            for (int di = 0; di < ND; ++di)
                #pragma unroll
                for (int w = 0; w < 16; ++w)
                    acc[di][w] = fmaf(Fv[di], w16[w], acc[di][w]);
        }
        #pragma unroll
        for (int di = 0; di < ND; ++di) {
            union { bf16 h[16]; uint4 q[2]; } pk;
            #pragma unroll
            for (int w = 0; w < 16; ++w) pk.h[w] = __float2bfloat16(acc[di][w]);
            bf16* dst = aout + (D2 + d0 + di) * WD;
            *(uint4*)dst       = pk.q[0];
            *(uint4*)(dst + 8) = pk.q[1];
        }
    }
}

// ---------------------------------------------------------------------------
// MFMA GEMM k64 (round-23, kept): templated BM, BK=64, 8-chunk swizzle,
// own-half reconstruction, split epilogue (fpm only rows < Msplit, fb only
// rows >= Msplit — skipped halves were never read).
// ---------------------------------------------------------------------------
template<int BM>
__global__ __launch_bounds__(256)
void gemm_mfma_k64(const bf16* __restrict__ A, const bf16* __restrict__ Bhi,
                   const bf16* __restrict__ Blo, const float* __restrict__ bias,
                   const float* __restrict__ ownf, const float* __restrict__ swb,
                   float* __restrict__ out_t, float* __restrict__ out_pm,
                   bf16* __restrict__ out_pmb, int Msplit, int m0, int K)
{
    constexpr int AE   = BM * 64;
    constexpr int BT   = 128 * 64;
    constexpr int BUFE = AE + 2 * BT;
    constexpr int MF   = BM / 32;
    constexpr int RA   = BM * 8 / 256;
    __shared__ __align__(16) char smem[2 * BUFE * 2];
    bf16* lds = (bf16*)smem;

    const int tid  = threadIdx.x;
    const int w    = tid >> 6;
    const int lane = tid & 63;
    const int wr   = w >> 1, wc = w & 1;
    const int mb   = (int)blockIdx.x * BM;
    const int gK   = lane >> 4;
    const int rL   = lane & 15;
    const int D2v  = K / 32;

    int rowA[RA], schA[RA];
    float sww[RA][8];
    const float* ownrow_g[RA];
    #pragma unroll
    for (int r = 0; r < RA; ++r) {
        const int slot = r * 256 + tid;
        rowA[r] = slot >> 3;
        const int ch = slot & 7;
        schA[r] = ch ^ (rowA[r] & 7);
        const int w0 = (schA[r] & 1) * 8;
        const float* sp = swb + (size_t)(mb + rowA[r]) * 16 + w0;
        const float4 a = *(const float4*)sp;
        const float4 b2 = *(const float4*)(sp + 4);
        sww[r][0] = a.x;  sww[r][1] = a.y;  sww[r][2] = a.z;  sww[r][3] = a.w;
        sww[r][4] = b2.x; sww[r][5] = b2.y; sww[r][6] = b2.z; sww[r][7] = b2.w;
        ownrow_g[r] = ownf + (size_t)(m0 + mb + rowA[r]) * D2v;
    }

    f32x4 acc[MF][4];
    #pragma unroll
    for (int i = 0; i < MF; ++i)
        #pragma unroll
        for (int j = 0; j < 4; ++j) acc[i][j] = (f32x4)0.f;

    const int nk = K / 64;
    const int nkOwn = nk / 2;

    auto stage = [&](int buf, int kt) {
        const int kb = kt * 64;
        const int bufo = buf * BUFE;
        if (kt < nkOwn) {
            #pragma unroll
            for (int r = 0; r < RA; ++r) {
                const int d = kt * 4 + (schA[r] >> 1);
                const float f = ownrow_g[r][d];
                union { bf16 h[8]; uint4 q; } pk;
                #pragma unroll
                for (int j = 0; j < 8; ++j) pk.h[j] = __float2bfloat16(f * sww[r][j]);
                *(uint4*)(lds + bufo + (r * 256 + tid) * 8) = pk.q;
            }
        } else {
            #pragma unroll
            for (int r = 0; r < RA; ++r)
                GLD16(A + (size_t)(mb + rowA[r]) * K + kb + (schA[r] << 3),
                      lds + bufo + ((r * 256 + w * 64) << 3));
        }
        #pragma unroll
        for (int i = 0; i < 4; ++i) {
            const int s2 = i * 256 + tid;
            const int row = s2 >> 3, ch = s2 & 7;
            const int sch = ch ^ (row & 7);
            const int wb = (i * 256 + w * 64) << 3;
            GLD16(Bhi + (size_t)row * K + kb + (sch << 3), lds + bufo + AE + wb);
            GLD16(Blo + (size_t)row * K + kb + (sch << 3), lds + bufo + AE + BT + wb);
        }
    };

    stage(0, 0);
    __syncthreads();

    for (int kt = 0; kt < nk; ++kt) {
        const int cur = kt & 1;
        if (kt + 1 < nk) stage(cur ^ 1, kt + 1);

        const bf16* la  = lds + cur * BUFE;
        const bf16* lbh = la + AE;
        const bf16* lbl = la + AE + BT;

        #pragma unroll
        for (int kk2 = 0; kk2 < 2; ++kk2) {
            const int cc = gK + kk2 * 4;
            bf16x8 af[MF], bh[4], bl[4];
            #pragma unroll
            for (int mf = 0; mf < MF; ++mf) {
                const int row = wr * (BM / 2) + mf * 16 + rL;
                af[mf] = *(const bf16x8*)(la + row * 64 + ((cc ^ (row & 7)) << 3));
            }
            #pragma unroll
            for (int nf = 0; nf < 4; ++nf) {
                const int col = wc * 64 + nf * 16 + rL;
                const int off = col * 64 + ((cc ^ (col & 7)) << 3);
                bh[nf] = *(const bf16x8*)(lbh + off);
                bl[nf] = *(const bf16x8*)(lbl + off);
            }
            #pragma unroll
            for (int mf = 0; mf < MF; ++mf)
                #pragma unroll
                for (int nf = 0; nf < 4; ++nf) {
                    acc[mf][nf] = __builtin_amdgcn_mfma_f32_16x16x32_bf16(af[mf], bh[nf], acc[mf][nf], 0, 0, 0);
                    acc[mf][nf] = __builtin_amdgcn_mfma_f32_16x16x32_bf16(af[mf], bl[nf], acc[mf][nf], 0, 0, 0);
                }
        }
        __syncthreads();
    }

    float (*tile)[133] = (float(*)[133])smem;
    #pragma unroll
    for (int mf = 0; mf < MF; ++mf)
        #pragma unroll
        for (int nf = 0; nf < 4; ++nf) {
            const int col = wc * 64 + nf * 16 + rL;
            const float bs = bias[col];
            #pragma unroll
            for (int qq = 0; qq < 4; ++qq) {
                const int rrow = wr * (BM / 2) + mf * 16 + gK * 4 + qq;
                const float v = acc[mf][nf][qq] + bs;
                tile[rrow][col] = v > 0.f ? v : 0.1f * v;
            }
        }
    __syncthreads();

    const int mrow = m0 + mb;
    const int b = mrow >> 12, n0 = mrow & (NPT - 1);
    for (int e = tid; e < BM * MIDD; e += 256) {
        const int o = e / BM, i = e % BM;
        out_t[((size_t)b * MIDD + o) * NPT + n0 + i] = tile[i][o];
    }
    if (out_pm && mrow < Msplit) {          // f1 side: f32 pm (cross-3 own)
        for (int e = tid; e < BM * MIDD; e += 256) {
            const int i = e >> 7, o = e & 127;
            out_pm[(size_t)(mrow + i) * MIDD + o] = tile[i][o];
        }
    }
    if (out_pmb && mrow >= Msplit) {        // f2 side: bf16 pm (cross-3 gather)
        for (int e = tid; e < BM * MIDD; e += 256) {
            const int i = e >> 7, o = e & 127;
            out_pmb[(size_t)(mrow + i) * MIDD + o] = __float2bfloat16(tile[i][o]);
        }
    }
}

// ---------------------------------------------------------------------------
extern "C" void kernel_launch(void* const* d_in, const int* in_sizes, int n_in,
                              void* d_out, int out_size, void* d_ws, size_t ws_size,
                              hipStream_t stream)
{
    (void)in_sizes; (void)n_in; (void)out_size;
    const float* pc1    = (const float*)d_in[0];
    const float* pc2    = (const float*)d_in[1];
    const float* feat1  = (const float*)d_in[2];
    const float* feat2  = (const float*)d_in[3];
    const float* wn1_w0 = (const float*)d_in[4];
    const float* wn1_b0 = (const float*)d_in[5];
    const float* wn1_w1 = (const float*)d_in[6];
    const float* wn1_b1 = (const float*)d_in[7];
    const float* wn1_w2 = (const float*)d_in[8];
    const float* wn1_b2 = (const float*)d_in[9];
    const float* lin1_w = (const float*)d_in[10];
    const float* lin1_b = (const float*)d_in[11];
    const float* wn2_w0 = (const float*)d_in[12];
    const float* wn2_b0 = (const float*)d_in[13];
    const float* wn2_w1 = (const float*)d_in[14];
    const float* wn2_b1 = (const float*)d_in[15];
    const float* wn2_w2 = (const float*)d_in[16];
    const float* wn2_b2 = (const float*)d_in[17];
    const float* lin2_w = (const float*)d_in[18];
    const float* lin2_b = (const float*)d_in[19];
    float* out = (float*)d_out;

    const int M  = BB * NPT;
    const int M2 = 2 * M;
    const int K1 = 2 * CDIM * WD;     // 2048
    const int K2 = 2 * MIDD * WD;     // 4096

    char* ws = (char*)d_ws;
    float* p1pm = (float*)ws;
    float* p2pm = p1pm + (size_t)M * CDIM;
    float* fpm  = p2pm + (size_t)M * CDIM;
    bf16*  p1b  = (bf16*)(fpm + (size_t)M2 * MIDD);
    bf16*  p2b  = p1b + (size_t)M * CDIM;
    bf16*  fb   = p2b + (size_t)M * CDIM;
    int* idx12  = (int*)(fb + (size_t)M2 * MIDD);
    int* idx21  = idx12 + (size_t)M * NBR;
    bf16* b1hi  = (bf16*)(idx21 + (size_t)M * NBR);
    bf16* b1lo  = b1hi + (size_t)MIDD * K1;
    bf16* b2hi  = b1lo + (size_t)MIDD * K1;
    bf16* b2lo  = b2hi + (size_t)MIDD * K2;
    float* swbuf = (float*)(b2lo + (size_t)MIDD * K2);
    bf16* aggbuf = (bf16*)(swbuf + (size_t)(M2 + 64) * 16);
    const size_t used = (size_t)((char*)aggbuf - ws);
    const size_t avail = ws_size > used ? ws_size - used : 0;

    float* f1t = out;
    float* fft = out + 2 * (size_t)BB * MIDD * NPT;

    pre_kernel<<<2048 + 2816, 256, 0, stream>>>(
        pc1, pc2, idx12, idx21,
        feat1, feat2, p1pm, p1b, p2pm, p2b,
        lin1_w, b1hi, b1lo, lin2_w, b2hi, b2lo);

    auto chunk_rows = [&](int K) -> int {
        long rows = (long)(avail / ((size_t)K * sizeof(bf16)));
        int cm = (int)(rows > M2 ? M2 : rows) & ~127;
        if (cm < 128) cm = 128;
        return cm;
    };

    {   // cross 1 + cross 2 merged (K = 2048); BM=64, BK=64
        const int CMr = chunk_rows(K1);
        for (int m0 = 0; m0 < M2; m0 += CMr) {
            const int cm = (M2 - m0 < CMr) ? (M2 - m0) : CMr;
            agg_kernel<CDIM, 8><<<cm / 8, 256, 0, stream>>>(
                pc1, pc2, p2b, idx12,
                pc2, pc1, p1b, idx21, M,
                wn1_w0, wn1_b0, wn1_w1, wn1_b1, wn1_w2, wn1_b2,
                aggbuf, swbuf, m0);
            gemm_mfma_k64<64><<<cm / 64, 256, 0, stream>>>(aggbuf, b1hi, b1lo, lin1_b,
                                                           p1pm, swbuf,
                                                           f1t, fpm, fb, M, m0, K1);
        }
    }
    {   // cross 3 (K = 4096); BM=32, BK=64
        const int CMr = chunk_rows(K2);
        for (int m0 = 0; m0 < M; m0 += CMr) {
            const int cm = (M - m0 < CMr) ? (M - m0) : CMr;
            agg_kernel<MIDD, 4><<<cm / 4, 256, 0, stream>>>(
                pc1, pc2, fb + (size_t)M * MIDD, idx12,
                nullptr, nullptr, nullptr, nullptr, M2,
                wn2_w0, wn2_b0, wn2_w1, wn2_b1, wn2_w2, wn2_b2,
                aggbuf, swbuf, m0);
            gemm_mfma_k64<32><<<cm / 32, 256, 0, stream>>>(aggbuf, b2hi, b2lo, lin2_b,
                                                           fpm, swbuf,
                                                           fft, nullptr, nullptr, 0, m0, K2);
        }
    }
}